// Round 1
// baseline (481.002 us; speedup 1.0000x reference)
//
#include <hip/hip_runtime.h>

// Fused LSTM: B=16384, T=60, IN=1, H=50, OUT=1.
// Layout: 256 WGs x 512 threads (8 waves). lane = batch element (64/WG).
// Wave w owns hidden units j = w + 8m (m=0..6, j<50); each thread computes
// all 4 gate rows for its units -> c-update is register-local.
// Only h is exchanged via LDS (2 barriers/step).

namespace {
constexpr int BTOT = 16384;
constexpr int TSTEPS = 60;
constexpr int HID = 50;
constexpr int HP = 52;   // padded w_hh row length (16B-aligned float4 rows)
constexpr int NB = 64;   // batch per workgroup
constexpr int NW = 8;    // waves per workgroup

__device__ __forceinline__ float fexp2(float x) {
#if __has_builtin(__builtin_amdgcn_exp2f)
  return __builtin_amdgcn_exp2f(x);
#else
  return exp2f(x);
#endif
}
__device__ __forceinline__ float frcp(float x) {
#if __has_builtin(__builtin_amdgcn_rcpf)
  return __builtin_amdgcn_rcpf(x);
#else
  return 1.0f / x;
#endif
}
__device__ __forceinline__ float sigm(float x) {
  // 1/(1+exp(-x)) = rcp(1 + exp2(-log2(e)*x))
  return frcp(1.0f + fexp2(-1.4426950408889634f * x));
}
__device__ __forceinline__ float tanh_(float x) {
  // tanh(x) = 1 - 2/(exp2(2*log2(e)*x) + 1)
  return fmaf(-2.0f, frcp(1.0f + fexp2(2.8853900817779268f * x)), 1.0f);
}
}  // namespace

__global__ __launch_bounds__(512, 2) void lstm_fused(
    const float* __restrict__ x,      // [B][60]
    const float* __restrict__ w_ih,   // [200] (IN=1)
    const float* __restrict__ w_hh,   // [200][50]
    const float* __restrict__ b_ih,   // [200]
    const float* __restrict__ b_hh,   // [200]
    const float* __restrict__ w_lin,  // [3000] = [t*50+j]
    const float* __restrict__ b_lin,  // [1]
    float* __restrict__ out)          // [B]
{
  __shared__ __align__(16) float wlds[200 * HP];  // 41600 B
  __shared__ __align__(16) float hbuf[HID * NB];  // 12800 B  [k][b]

  const int tid = threadIdx.x;
  const int lane = tid & 63;
  const int wv = __builtin_amdgcn_readfirstlane(tid >> 6);  // wave id, uniform

  // Stage w_hh -> LDS, rows padded to 52 (pad = 0).
  for (int idx = tid; idx < 200 * HP; idx += 512) {
    const int r = idx / HP;
    const int k = idx - r * HP;
    wlds[idx] = (k < HID) ? w_hh[r * HID + k] : 0.0f;
  }
  __syncthreads();

  const long gb = (long)blockIdx.x * NB + lane;  // global batch index

  float h[HP];
#pragma unroll
  for (int k = 0; k < HP; ++k) h[k] = 0.0f;  // h[50],h[51] stay 0 (pad)
  float c[7];
#pragma unroll
  for (int m = 0; m < 7; ++m) c[m] = 0.0f;
  float oacc = 0.0f;

#pragma unroll 1
  for (int t = 0; t < TSTEPS; ++t) {
    const float xv = x[gb * TSTEPS + t];  // per-lane, L1-resident after step 0

#pragma unroll
    for (int m = 0; m < 7; ++m) {
      const int j = wv + 8 * m;  // wave-uniform
      if (j < HID) {             // uniform branch (s_cbranch)
        const int ri = j, rf = HID + j, rg = 2 * HID + j, ro = 3 * HID + j;
        // init with x-projection + both biases (uniform scalar loads)
        float ai = fmaf(xv, w_ih[ri], b_ih[ri] + b_hh[ri]);
        float af = fmaf(xv, w_ih[rf], b_ih[rf] + b_hh[rf]);
        float ag = fmaf(xv, w_ih[rg], b_ih[rg] + b_hh[rg]);
        float ao = fmaf(xv, w_ih[ro], b_ih[ro] + b_hh[ro]);
        const float4* wi4 = (const float4*)(wlds + ri * HP);
        const float4* wf4 = (const float4*)(wlds + rf * HP);
        const float4* wg4 = (const float4*)(wlds + rg * HP);
        const float4* wo4 = (const float4*)(wlds + ro * HP);
#pragma unroll
        for (int q = 0; q < HP / 4; ++q) {
          const float4 a4 = wi4[q];  // uniform address -> LDS broadcast
          const float4 b4 = wf4[q];
          const float4 g4 = wg4[q];
          const float4 o4 = wo4[q];
          const float h0 = h[4 * q + 0], h1 = h[4 * q + 1];
          const float h2 = h[4 * q + 2], h3 = h[4 * q + 3];
          ai = fmaf(a4.x, h0, ai); af = fmaf(b4.x, h0, af);
          ag = fmaf(g4.x, h0, ag); ao = fmaf(o4.x, h0, ao);
          ai = fmaf(a4.y, h1, ai); af = fmaf(b4.y, h1, af);
          ag = fmaf(g4.y, h1, ag); ao = fmaf(o4.y, h1, ao);
          ai = fmaf(a4.z, h2, ai); af = fmaf(b4.z, h2, af);
          ag = fmaf(g4.z, h2, ag); ao = fmaf(o4.z, h2, ao);
          ai = fmaf(a4.w, h3, ai); af = fmaf(b4.w, h3, af);
          ag = fmaf(g4.w, h3, ag); ao = fmaf(o4.w, h3, ao);
        }
        const float ig = sigm(ai);
        const float fg = sigm(af);
        const float gg = tanh_(ag);
        const float og = sigm(ao);
        const float cn = fmaf(fg, c[m], ig * gg);
        c[m] = cn;
        const float hn = og * tanh_(cn);
        hbuf[j * NB + lane] = hn;                  // stride-1 across lanes
        oacc = fmaf(hn, w_lin[t * HID + j], oacc); // uniform scalar load
      }
    }
    __syncthreads();
// reload full h for next step (stride-1 across lanes, conflict-free)
#pragma unroll
    for (int k = 0; k < HID; ++k) h[k] = hbuf[k * NB + lane];
    __syncthreads();
  }

  // reduce per-wave output partials across the 8 waves (reuse hbuf)
  hbuf[wv * NB + lane] = oacc;
  __syncthreads();
  if (tid < NB) {
    float s = b_lin[0];
#pragma unroll
    for (int q = 0; q < NW; ++q) s += hbuf[q * NB + tid];
    out[(long)blockIdx.x * NB + tid] = s;
  }
}

extern "C" void kernel_launch(void* const* d_in, const int* in_sizes, int n_in,
                              void* d_out, int out_size, void* d_ws, size_t ws_size,
                              hipStream_t stream) {
  const float* x     = (const float*)d_in[0];
  const float* w_ih  = (const float*)d_in[1];
  const float* w_hh  = (const float*)d_in[2];
  const float* b_ih  = (const float*)d_in[3];
  const float* b_hh  = (const float*)d_in[4];
  const float* w_lin = (const float*)d_in[5];
  const float* b_lin = (const float*)d_in[6];
  float* out = (float*)d_out;

  dim3 grid(BTOT / NB);  // 256 workgroups -> one per CU
  dim3 block(512);
  lstm_fused<<<grid, block, 0, stream>>>(x, w_ih, w_hh, b_ih, b_hh, w_lin,
                                         b_lin, out);
}